// Round 2
// baseline (879.639 us; speedup 1.0000x reference)
//
#include <hip/hip_runtime.h>

// GCN layer: out = sum_r segment_sum(vals_r * inp[src_r], dst_r) @ W_r
// Plan: h_r = inp @ W_r (dense GEMM, 8x8 reg tile, LDS-balanced), then build
// CSR-by-dst on device (hist/scan/fill) and GATHER (no f32 atomics):
//   out[d] = sum_{edges into d} val * h[r, src].
// N=50000, R=8, E=100000, IN=OUT=128, f32.

constexpr int IN  = 128;
constexpr int OUT = 128;
constexpr int BM  = 128;   // gemm rows per block
constexpr int BK  = 32;    // gemm k-chunk

// ---------------- GEMM: h[by] = inp @ W[rel_base+by] ------------------------
// 256 threads, 128x128 tile, 8 rows x 8 cols per thread (split 4+4 at +64 to
// keep every LDS access <=2-way). A tile XOR-swizzled: slot kq^(row&7).
__global__ __launch_bounds__(256) void gemm_kernel(
    const float* __restrict__ inp, const float* __restrict__ weights,
    float* __restrict__ h, int rel_base, long long h_stride,
    int node_lo, int node_hi)
{
    const int r = rel_base + blockIdx.y;
    const float* W = weights + (size_t)r * IN * OUT;
    float* hout = h + (size_t)blockIdx.y * h_stride;

    __shared__ float4 As4[BM * (BK / 4)];   // 16 KB, [row][kq ^ (row&7)]
    __shared__ float4 Ws4[BK * (OUT / 4)];  // 16 KB, [k][c4]

    const int tid = threadIdx.x;
    const int c4  = tid & 15;         // cols c4*4..+3 and c4*4+64..+67
    const int r0  = (tid >> 4) * 4;   // rows r0..r0+3 and r0+64..+67

    const int row0 = node_lo + blockIdx.x * BM;

    float4 acc[8][2];
    #pragma unroll
    for (int i = 0; i < 8; ++i)
        #pragma unroll
        for (int hh = 0; hh < 2; ++hh)
            acc[i][hh] = make_float4(0.f, 0.f, 0.f, 0.f);

    for (int kc = 0; kc < IN / BK; ++kc) {
        __syncthreads();
        {   // stage W chunk [kc*BK .. +BK) x OUT : linear float4 copy
            const float4* Wg = (const float4*)(W + (size_t)kc * BK * OUT);
            #pragma unroll
            for (int p = 0; p < 4; ++p)
                Ws4[tid + p * 256] = Wg[tid + p * 256];
        }
        {   // stage A: BM rows x BK cols, row-major, XOR-swizzled k-quad slot
            #pragma unroll
            for (int p = 0; p < 4; ++p) {
                const int item = tid + p * 256;
                const int rowl = item >> 3;       // 0..127
                const int kq   = item & 7;        // 0..7
                const int grow = row0 + rowl;
                float4 v = make_float4(0.f, 0.f, 0.f, 0.f);
                if (grow < node_hi)
                    v = *(const float4*)(inp + (size_t)grow * IN + kc * BK + kq * 4);
                As4[rowl * 8 + (kq ^ (rowl & 7))] = v;
            }
        }
        __syncthreads();

        #pragma unroll
        for (int k4 = 0; k4 < 8; ++k4) {
            float4 a[8], w[8];
            #pragma unroll
            for (int i = 0; i < 4; ++i) {
                const int rlo = r0 + i, rhi = r0 + 64 + i;
                a[i]     = As4[rlo * 8 + (k4 ^ (rlo & 7))];
                a[i + 4] = As4[rhi * 8 + (k4 ^ (rhi & 7))];
            }
            #pragma unroll
            for (int kk = 0; kk < 4; ++kk) {
                w[kk]     = Ws4[(k4 * 4 + kk) * 32 + c4];
                w[kk + 4] = Ws4[(k4 * 4 + kk) * 32 + c4 + 16];
            }
            #pragma unroll
            for (int i = 0; i < 8; ++i) {
                #pragma unroll
                for (int hh = 0; hh < 2; ++hh) {
                    acc[i][hh].x += a[i].x*w[hh*4+0].x + a[i].y*w[hh*4+1].x
                                  + a[i].z*w[hh*4+2].x + a[i].w*w[hh*4+3].x;
                    acc[i][hh].y += a[i].x*w[hh*4+0].y + a[i].y*w[hh*4+1].y
                                  + a[i].z*w[hh*4+2].y + a[i].w*w[hh*4+3].y;
                    acc[i][hh].z += a[i].x*w[hh*4+0].z + a[i].y*w[hh*4+1].z
                                  + a[i].z*w[hh*4+2].z + a[i].w*w[hh*4+3].z;
                    acc[i][hh].w += a[i].x*w[hh*4+0].w + a[i].y*w[hh*4+1].w
                                  + a[i].z*w[hh*4+2].w + a[i].w*w[hh*4+3].w;
                }
            }
        }
    }

    #pragma unroll
    for (int i = 0; i < 8; ++i) {
        const int rl = (i < 4) ? (r0 + i) : (r0 + 64 + (i - 4));
        const int grow = row0 + rl;
        if (grow < node_hi) {
            float* dstp = hout + (size_t)(grow - node_lo) * OUT;
            *(float4*)(dstp + c4 * 4)      = acc[i][0];
            *(float4*)(dstp + c4 * 4 + 64) = acc[i][1];
        }
    }
}

// ---------------- CSR build -------------------------------------------------
__global__ __launch_bounds__(256) void hist_kernel(
    const int* __restrict__ dst, int* __restrict__ counts, int n)
{
    const int i = blockIdx.x * 256 + threadIdx.x;
    if (i < n) atomicAdd(&counts[dst[i]], 1);
}

__global__ __launch_bounds__(1024) void scan_kernel(
    const int* __restrict__ counts, int* __restrict__ offs,
    int* __restrict__ cursor, int n)
{
    __shared__ int ps[1024];
    const int tid = threadIdx.x;
    const int chunk = (n + 1023) >> 10;
    const int lo = tid * chunk;
    const int hi = (lo + chunk < n) ? lo + chunk : n;
    int s = 0;
    for (int i = lo; i < hi; ++i) s += counts[i];
    ps[tid] = s;
    __syncthreads();
    for (int d = 1; d < 1024; d <<= 1) {
        const int v = (tid >= d) ? ps[tid - d] : 0;
        __syncthreads();
        ps[tid] += v;
        __syncthreads();
    }
    int run = ps[tid] - s;   // exclusive prefix
    for (int i = lo; i < hi; ++i) {
        offs[i] = run; cursor[i] = run;
        run += counts[i];
    }
    if (tid == 1023) offs[n] = ps[1023];
}

// src/dst/vals pre-offset to this pass's first relation; by = local relation.
__global__ __launch_bounds__(256) void fill_kernel(
    const int* __restrict__ src, const int* __restrict__ dst,
    const float* __restrict__ vals, int* __restrict__ cursor,
    int2* __restrict__ csr, int n_edges, int n_nodes)
{
    const int e = blockIdx.x * 256 + threadIdx.x;
    if (e >= n_edges) return;
    const size_t g = (size_t)blockIdx.y * n_edges + e;
    const int d = dst[g];
    const int pos = atomicAdd(&cursor[d], 1);
    csr[pos] = make_int2(blockIdx.y * n_nodes + src[g], __float_as_int(vals[g]));
}

// ---------------- Gather: out[d] = sum val * h[rec] -------------------------
__global__ __launch_bounds__(256) void gather_kernel(
    const float* __restrict__ h, const int2* __restrict__ csr,
    const int* __restrict__ offs, float* __restrict__ out,
    int n_nodes, int accum)
{
    const int node = blockIdx.x * 8 + (threadIdx.x >> 5);
    const int lane = threadIdx.x & 31;
    if (node >= n_nodes) return;
    const int b = offs[node], e = offs[node + 1];
    float4* op = (float4*)(out + (size_t)node * OUT);
    float4 acc = accum ? op[lane] : make_float4(0.f, 0.f, 0.f, 0.f);
    for (int j = b; j < e; ++j) {
        const int2 rec = csr[j];
        const float v = __int_as_float(rec.y);
        const float4 hv = ((const float4*)(h + (size_t)rec.x * OUT))[lane];
        acc.x += v * hv.x; acc.y += v * hv.y;
        acc.z += v * hv.z; acc.w += v * hv.w;
    }
    op[lane] = acc;
}

// ---------------- fallback scatter (atomic) ---------------------------------
__global__ __launch_bounds__(256) void scatter_kernel(
    const float* __restrict__ h, const int* __restrict__ src,
    const int* __restrict__ dst, const float* __restrict__ vals,
    float* __restrict__ out, int rel_base, long long h_stride,
    int node_lo, int node_hi, int n_edges)
{
    const int r = rel_base + blockIdx.y;
    const float* hrel = h + (size_t)blockIdx.y * h_stride;
    const int e = blockIdx.x * 8 + (threadIdx.x >> 5);
    if (e >= n_edges) return;
    const int lane = threadIdx.x & 31;
    const size_t eidx = (size_t)r * n_edges + e;
    const int s = src[eidx];
    if (s < node_lo || s >= node_hi) return;
    const int d = dst[eidx];
    const float v = vals[eidx];
    const float* hrow = hrel + (size_t)(s - node_lo) * OUT;
    float* orow = out + (size_t)d * OUT;
    #pragma unroll
    for (int kk = 0; kk < 4; ++kk) {
        const int j = lane + kk * 32;
        __hip_atomic_fetch_add(orow + j, v * hrow[j], __ATOMIC_RELAXED,
                               __HIP_MEMORY_SCOPE_AGENT);
    }
}

extern "C" void kernel_launch(void* const* d_in, const int* in_sizes, int n_in,
                              void* d_out, int out_size, void* d_ws, size_t ws_size,
                              hipStream_t stream) {
    const float* inp     = (const float*)d_in[0];
    const int*   src     = (const int*)  d_in[1];
    const int*   dst     = (const int*)  d_in[2];
    const float* vals    = (const float*)d_in[3];
    const float* weights = (const float*)d_in[4];
    float* out = (float*)d_out;

    const int n_nodes = in_sizes[0] / IN;            // 50000
    const int n_rel   = in_sizes[4] / (IN * OUT);    // 8
    const int n_edges = in_sizes[1] / n_rel;         // 100000

    auto align_up = [](size_t x) { return (x + 255) & ~(size_t)255; };
    const size_t sz_counts = align_up((size_t)n_nodes * 4);
    const size_t sz_offs   = align_up((size_t)(n_nodes + 1) * 4);
    const size_t sz_cursor = align_up((size_t)n_nodes * 4);
    const size_t aux = sz_counts + sz_offs + sz_cursor;

    // Pick max relations-per-pass RP that fits: aux + csr(RP) + h(RP)
    int RP = 0;
    for (int rp = n_rel; rp >= 1; --rp) {
        const size_t need = aux + align_up((size_t)rp * n_edges * 8)
                          + (size_t)rp * n_nodes * OUT * 4;
        if (need <= ws_size) { RP = rp; break; }
    }

    if (RP >= 1) {
        char* p = (char*)d_ws;
        int*  counts = (int*)p;        p += sz_counts;
        int*  offs   = (int*)p;        p += sz_offs;
        int*  cursor = (int*)p;        p += sz_cursor;
        int2* csr    = (int2*)p;       p += align_up((size_t)RP * n_edges * 8);
        float* h     = (float*)p;

        const long long hstride = (long long)n_nodes * OUT;
        const int gemm_gx = (n_nodes + BM - 1) / BM;
        const int gath_gx = (n_nodes + 7) / 8;

        for (int rb = 0; rb < n_rel; rb += RP) {
            const int nr = (rb + RP <= n_rel) ? RP : (n_rel - rb);
            const size_t eoff = (size_t)rb * n_edges;

            hipMemsetAsync(counts, 0, (size_t)n_nodes * 4, stream);
            {
                const int tot = nr * n_edges;
                hist_kernel<<<(tot + 255) / 256, 256, 0, stream>>>(
                    dst + eoff, counts, tot);
            }
            scan_kernel<<<1, 1024, 0, stream>>>(counts, offs, cursor, n_nodes);
            {
                dim3 g((n_edges + 255) / 256, nr);
                fill_kernel<<<g, 256, 0, stream>>>(
                    src + eoff, dst + eoff, vals + eoff, cursor, csr,
                    n_edges, n_nodes);
            }
            {
                dim3 g(gemm_gx, nr);
                gemm_kernel<<<g, 256, 0, stream>>>(
                    inp, weights, h, rb, hstride, 0, n_nodes);
            }
            gather_kernel<<<gath_gx, 256, 0, stream>>>(
                h, csr, offs, out, n_nodes, rb > 0 ? 1 : 0);
        }
    } else {
        // Ultimate fallback: chunked gemm + atomic scatter (round-1 path).
        hipMemsetAsync(out, 0, (size_t)n_nodes * OUT * sizeof(float), stream);
        float* h = (float*)d_ws;
        int chunk = (int)(ws_size / (OUT * sizeof(float)));
        if (chunk < BM) chunk = BM;
        if (chunk > n_nodes) chunk = n_nodes;
        const int sgx = (n_edges + 7) / 8;
        for (int r = 0; r < n_rel; ++r) {
            for (int lo = 0; lo < n_nodes; lo += chunk) {
                const int hi = (lo + chunk < n_nodes) ? (lo + chunk) : n_nodes;
                gemm_kernel<<<(hi - lo + BM - 1) / BM, 256, 0, stream>>>(
                    inp, weights, h, r, 0, lo, hi);
                dim3 sg(sgx, 1);
                scatter_kernel<<<sg, 256, 0, stream>>>(
                    h, src, dst, vals, out, r, 0, lo, hi, n_edges);
            }
        }
    }
}

// Round 3
// 382.350 us; speedup vs baseline: 2.3006x; 2.3006x over previous
//
#include <hip/hip_runtime.h>

// GCN layer: out = sum_r segment_sum(vals_r * inp[src_r], dst_r) @ W_r
// Strategy:
//   1) h[r] = inp @ W_r  -- thread-per-row GEMM, W via wave-uniform s_loads,
//      A via per-lane 64B row chunks (no LDS, ~60 VGPR, acc[32]).
//   2) bucket CSR-by-dst (no scan): bucket[d*CAP + atomicAdd(cnt[d])],
//      overflow -> spill list (atomic cleanup kernel, expected ~0 edges).
//   3) gather: out[d] = sum val*h[rec], 4-way unrolled for MLP, one
//      coalesced float4 store per (node,lane). No f32 atomics on hot path.
// N=50000, R=8, E=100000, IN=OUT=128, f32.

constexpr int IN  = 128;
constexpr int OUT = 128;

// ---------------- GEMM: thread = one row x 32 cols --------------------------
// blockIdx.y = rel_local*4 + colgroup. W loads are wave-uniform (blockIdx +
// loop vars only) and all pointers are __restrict__ with no global stores in
// the K loop -> compiler emits s_load; FMA = v_fmac_f32 acc, s_w, v_a.
#define GEMM_STEP(AVAL, WP)                                            \
    {                                                                  \
        const float a_ = (AVAL);                                       \
        const float* __restrict__ wp_ = (WP);                          \
        _Pragma("unroll")                                              \
        for (int j = 0; j < 32; ++j) acc[j] = fmaf(a_, wp_[j], acc[j]);\
    }

__global__ __launch_bounds__(256) void gemm_kernel(
    const float* __restrict__ inp, const float* __restrict__ weights,
    float* __restrict__ h, int rel_base, int n_nodes)
{
    const int rel_local = blockIdx.y >> 2;
    const int c0 = (blockIdx.y & 3) * 32;
    const int row = blockIdx.x * 256 + threadIdx.x;
    if (row >= n_nodes) return;

    const float* __restrict__ Wr =
        weights + (size_t)(rel_base + rel_local) * IN * OUT + c0;
    const float* __restrict__ arow = inp + (size_t)row * IN;

    float acc[32];
    #pragma unroll
    for (int j = 0; j < 32; ++j) acc[j] = 0.f;

    #pragma unroll 1
    for (int kc = 0; kc < 8; ++kc) {          // 16 k per iteration
        const float* __restrict__ ap = arow + kc * 16;
        const float4 b0 = *(const float4*)(ap + 0);
        const float4 b1 = *(const float4*)(ap + 4);
        const float4 b2 = *(const float4*)(ap + 8);
        const float4 b3 = *(const float4*)(ap + 12);
        const float* __restrict__ Wk = Wr + (size_t)(kc * 16) * OUT;
        GEMM_STEP(b0.x, Wk + 0 * OUT)  GEMM_STEP(b0.y, Wk + 1 * OUT)
        GEMM_STEP(b0.z, Wk + 2 * OUT)  GEMM_STEP(b0.w, Wk + 3 * OUT)
        GEMM_STEP(b1.x, Wk + 4 * OUT)  GEMM_STEP(b1.y, Wk + 5 * OUT)
        GEMM_STEP(b1.z, Wk + 6 * OUT)  GEMM_STEP(b1.w, Wk + 7 * OUT)
        GEMM_STEP(b2.x, Wk + 8 * OUT)  GEMM_STEP(b2.y, Wk + 9 * OUT)
        GEMM_STEP(b2.z, Wk + 10 * OUT) GEMM_STEP(b2.w, Wk + 11 * OUT)
        GEMM_STEP(b3.x, Wk + 12 * OUT) GEMM_STEP(b3.y, Wk + 13 * OUT)
        GEMM_STEP(b3.z, Wk + 14 * OUT) GEMM_STEP(b3.w, Wk + 15 * OUT)
    }

    float* __restrict__ hp =
        h + ((size_t)rel_local * n_nodes + row) * OUT + c0;
    #pragma unroll
    for (int j4 = 0; j4 < 8; ++j4)
        *(float4*)(hp + j4 * 4) = make_float4(acc[j4 * 4 + 0], acc[j4 * 4 + 1],
                                              acc[j4 * 4 + 2], acc[j4 * 4 + 3]);
}

// ---------------- bucket fill (no scan) -------------------------------------
// counts[n_nodes] followed by spill_cnt at counts[n_nodes].
__global__ __launch_bounds__(256) void fill_kernel(
    const int* __restrict__ src, const int* __restrict__ dst,
    const float* __restrict__ vals, int* __restrict__ counts,
    int2* __restrict__ bucket, int4* __restrict__ spill,
    int* __restrict__ spill_cnt, int n_edges, int n_nodes,
    int cap, int spill_max)
{
    const int e = blockIdx.x * 256 + threadIdx.x;
    if (e >= n_edges) return;
    const size_t g = (size_t)blockIdx.y * n_edges + e;
    const int d = dst[g];
    const int enc = blockIdx.y * n_nodes + src[g];   // h row index
    const int pos = atomicAdd(&counts[d], 1);
    if (pos < cap) {
        bucket[(size_t)d * cap + pos] = make_int2(enc, __float_as_int(vals[g]));
    } else {
        const int sp = atomicAdd(spill_cnt, 1);
        if (sp < spill_max)
            spill[sp] = make_int4(d, enc, __float_as_int(vals[g]), 0);
    }
}

// ---------------- gather ----------------------------------------------------
__global__ __launch_bounds__(256) void gather_kernel(
    const float* __restrict__ h, const int2* __restrict__ bucket,
    const int* __restrict__ counts, float* __restrict__ out,
    int n_nodes, int cap, int accum)
{
    const int node = blockIdx.x * 8 + (threadIdx.x >> 5);
    const int lane = threadIdx.x & 31;
    if (node >= n_nodes) return;
    int cnt = counts[node];
    if (cnt > cap) cnt = cap;
    const int2* __restrict__ b = bucket + (size_t)node * cap;
    float4* __restrict__ op = (float4*)(out + (size_t)node * OUT);

    float4 acc = accum ? op[lane] : make_float4(0.f, 0.f, 0.f, 0.f);
    int j = 0;
    for (; j + 4 <= cnt; j += 4) {      // 4 independent h-row loads in flight
        const int2 r0 = b[j], r1 = b[j + 1], r2 = b[j + 2], r3 = b[j + 3];
        const float4 h0 = ((const float4*)(h + (size_t)r0.x * OUT))[lane];
        const float4 h1 = ((const float4*)(h + (size_t)r1.x * OUT))[lane];
        const float4 h2 = ((const float4*)(h + (size_t)r2.x * OUT))[lane];
        const float4 h3 = ((const float4*)(h + (size_t)r3.x * OUT))[lane];
        const float v0 = __int_as_float(r0.y), v1 = __int_as_float(r1.y);
        const float v2 = __int_as_float(r2.y), v3 = __int_as_float(r3.y);
        acc.x += v0*h0.x + v1*h1.x + v2*h2.x + v3*h3.x;
        acc.y += v0*h0.y + v1*h1.y + v2*h2.y + v3*h3.y;
        acc.z += v0*h0.z + v1*h1.z + v2*h2.z + v3*h3.z;
        acc.w += v0*h0.w + v1*h1.w + v2*h2.w + v3*h3.w;
    }
    for (; j < cnt; ++j) {
        const int2 r0 = b[j];
        const float v = __int_as_float(r0.y);
        const float4 hv = ((const float4*)(h + (size_t)r0.x * OUT))[lane];
        acc.x += v * hv.x; acc.y += v * hv.y;
        acc.z += v * hv.z; acc.w += v * hv.w;
    }
    op[lane] = acc;
}

// ---------------- spill cleanup (expected ~0..2K edges) ---------------------
__global__ __launch_bounds__(256) void spill_kernel(
    const float* __restrict__ h, const int4* __restrict__ spill,
    const int* __restrict__ spill_cnt, float* __restrict__ out,
    int spill_max)
{
    int n = *spill_cnt;
    if (n > spill_max) n = spill_max;
    const int w = (blockIdx.x * 256 + threadIdx.x) >> 6;  // wave id
    const int lane = threadIdx.x & 63;
    const int nw = gridDim.x * 4;
    for (int i = w; i < n; i += nw) {
        const int4 s = spill[i];
        const float v = __int_as_float(s.z);
        const float* __restrict__ hr = h + (size_t)s.y * OUT;
        float* __restrict__ orow = out + (size_t)s.x * OUT;
        __hip_atomic_fetch_add(orow + lane, v * hr[lane],
                               __ATOMIC_RELAXED, __HIP_MEMORY_SCOPE_AGENT);
        __hip_atomic_fetch_add(orow + lane + 64, v * hr[lane + 64],
                               __ATOMIC_RELAXED, __HIP_MEMORY_SCOPE_AGENT);
    }
}

// ---------------- last-resort scatter (atomic, per relation) ----------------
__global__ __launch_bounds__(256) void scatter_kernel(
    const float* __restrict__ h, const int* __restrict__ src,
    const int* __restrict__ dst, const float* __restrict__ vals,
    float* __restrict__ out, int n_edges)
{
    const int e = blockIdx.x * 8 + (threadIdx.x >> 5);
    if (e >= n_edges) return;
    const int lane = threadIdx.x & 31;
    const int s = src[e];
    const int d = dst[e];
    const float v = vals[e];
    const float* __restrict__ hrow = h + (size_t)s * OUT;
    float* __restrict__ orow = out + (size_t)d * OUT;
    #pragma unroll
    for (int kk = 0; kk < 4; ++kk) {
        const int j = lane + kk * 32;
        __hip_atomic_fetch_add(orow + j, v * hrow[j], __ATOMIC_RELAXED,
                               __HIP_MEMORY_SCOPE_AGENT);
    }
}

extern "C" void kernel_launch(void* const* d_in, const int* in_sizes, int n_in,
                              void* d_out, int out_size, void* d_ws, size_t ws_size,
                              hipStream_t stream) {
    const float* inp     = (const float*)d_in[0];
    const int*   src     = (const int*)  d_in[1];
    const int*   dst     = (const int*)  d_in[2];
    const float* vals    = (const float*)d_in[3];
    const float* weights = (const float*)d_in[4];
    float* out = (float*)d_out;

    const int n_nodes = in_sizes[0] / IN;            // 50000
    const int n_rel   = in_sizes[4] / (IN * OUT);    // 8
    const int n_edges = in_sizes[1] / n_rel;         // 100000

    auto align_up = [](size_t x) { return (x + 255) & ~(size_t)255; };
    const int SPILL_MAX = 65536;
    const size_t sz_counts = align_up((size_t)(n_nodes + 1) * 4);
    const size_t sz_spill  = align_up((size_t)SPILL_MAX * 16);

    const int gemm_gx = (n_nodes + 255) / 256;
    const int gath_gx = (n_nodes + 7) / 8;
    const int fill_gx = (n_edges + 255) / 256;

    // ---- full path: all relations at once, bucket CSR ----
    {
        const size_t sz_h = (size_t)n_rel * n_nodes * OUT * 4;
        int cap = 0;
        const int caps[] = {64, 48, 32, 24, 20};
        for (int c : caps) {
            const size_t need = sz_h + sz_counts + sz_spill
                              + align_up((size_t)n_nodes * c * 8);
            if (need <= ws_size) { cap = c; break; }
        }
        if (cap > 0) {
            char* p = (char*)d_ws;
            float* h      = (float*)p;  p += sz_h;
            int*   counts = (int*)p;    p += sz_counts;
            int4*  spill  = (int4*)p;   p += sz_spill;
            int2*  bucket = (int2*)p;
            int*   spill_cnt = counts + n_nodes;

            dim3 gg(gemm_gx, n_rel * 4);
            gemm_kernel<<<gg, 256, 0, stream>>>(inp, weights, h, 0, n_nodes);
            hipMemsetAsync(counts, 0, (size_t)(n_nodes + 1) * 4, stream);
            dim3 fg(fill_gx, n_rel);
            fill_kernel<<<fg, 256, 0, stream>>>(src, dst, vals, counts, bucket,
                                                spill, spill_cnt, n_edges,
                                                n_nodes, cap, SPILL_MAX);
            gather_kernel<<<gath_gx, 256, 0, stream>>>(h, bucket, counts, out,
                                                       n_nodes, cap, 0);
            spill_kernel<<<128, 256, 0, stream>>>(h, spill, spill_cnt, out,
                                                  SPILL_MAX);
            return;
        }
    }

    // ---- per-relation path: h for one relation at a time ----
    {
        const size_t sz_h = (size_t)n_nodes * OUT * 4;
        int cap = 0;
        const int caps[] = {16, 12, 8};
        for (int c : caps) {
            const size_t need = sz_h + sz_counts + sz_spill
                              + align_up((size_t)n_nodes * c * 8);
            if (need <= ws_size) { cap = c; break; }
        }
        if (cap > 0) {
            char* p = (char*)d_ws;
            float* h      = (float*)p;  p += sz_h;
            int*   counts = (int*)p;    p += sz_counts;
            int4*  spill  = (int4*)p;   p += sz_spill;
            int2*  bucket = (int2*)p;
            int*   spill_cnt = counts + n_nodes;

            for (int r = 0; r < n_rel; ++r) {
                const size_t eoff = (size_t)r * n_edges;
                dim3 gg(gemm_gx, 4);
                gemm_kernel<<<gg, 256, 0, stream>>>(inp, weights, h, r, n_nodes);
                hipMemsetAsync(counts, 0, (size_t)(n_nodes + 1) * 4, stream);
                dim3 fg(fill_gx, 1);
                fill_kernel<<<fg, 256, 0, stream>>>(src + eoff, dst + eoff,
                                                    vals + eoff, counts, bucket,
                                                    spill, spill_cnt, n_edges,
                                                    n_nodes, cap, SPILL_MAX);
                gather_kernel<<<gath_gx, 256, 0, stream>>>(h, bucket, counts,
                                                           out, n_nodes, cap,
                                                           r > 0 ? 1 : 0);
                spill_kernel<<<128, 256, 0, stream>>>(h, spill, spill_cnt, out,
                                                      SPILL_MAX);
            }
            return;
        }
    }

    // ---- last resort: per-relation gemm + atomic scatter ----
    {
        float* h = (float*)d_ws;
        hipMemsetAsync(out, 0, (size_t)n_nodes * OUT * 4, stream);
        const int sgx = (n_edges + 7) / 8;
        for (int r = 0; r < n_rel; ++r) {
            const size_t eoff = (size_t)r * n_edges;
            dim3 gg(gemm_gx, 4);
            gemm_kernel<<<gg, 256, 0, stream>>>(inp, weights, h, r, n_nodes);
            scatter_kernel<<<sgx, 256, 0, stream>>>(h, src + eoff, dst + eoff,
                                                    vals + eoff, out, n_edges);
        }
    }
}

// Round 4
// 223.761 us; speedup vs baseline: 3.9312x; 1.7087x over previous
//
#include <hip/hip_runtime.h>

// GCN layer: out = sum_r segment_sum(vals_r * inp[src_r], dst_r) @ W_r
// Round 4: bf16 MFMA GEMM (h = inp @ W_r in bf16), bucket CSR-by-dst,
// gather with bf16 h. N=50000, R=8, E=100000, IN=OUT=128.

constexpr int IN  = 128;
constexpr int OUT = 128;
constexpr int LDK = 136;   // padded LDS row (bf16 elems) = 272 B

typedef __attribute__((ext_vector_type(8))) short bf16x8;
typedef __attribute__((ext_vector_type(4))) float f32x4;

__device__ inline unsigned short f2bf(float f) {
    unsigned int u = __float_as_uint(f);
    u += 0x7fffu + ((u >> 16) & 1u);          // RNE
    return (unsigned short)(u >> 16);
}
__device__ inline float bflo(unsigned int u) { return __uint_as_float(u << 16); }
__device__ inline float bfhi(unsigned int u) { return __uint_as_float(u & 0xffff0000u); }

// ---------------- converts --------------------------------------------------
__global__ __launch_bounds__(256) void conv_inp_kernel(
    const float* __restrict__ x, unsigned short* __restrict__ y, int n8)
{
    const int i = blockIdx.x * 256 + threadIdx.x;
    if (i >= n8) return;
    const float4 a = ((const float4*)x)[i * 2];
    const float4 b = ((const float4*)x)[i * 2 + 1];
    uint4 o;
    o.x = (unsigned)f2bf(a.x) | ((unsigned)f2bf(a.y) << 16);
    o.y = (unsigned)f2bf(a.z) | ((unsigned)f2bf(a.w) << 16);
    o.z = (unsigned)f2bf(b.x) | ((unsigned)f2bf(b.y) << 16);
    o.w = (unsigned)f2bf(b.z) | ((unsigned)f2bf(b.w) << 16);
    ((uint4*)y)[i] = o;
}

// Wt[r][n][k] = W[r][k][n], bf16
__global__ __launch_bounds__(256) void conv_w_kernel(
    const float* __restrict__ w, unsigned short* __restrict__ wt, int total)
{
    const int t = blockIdx.x * 256 + threadIdx.x;
    if (t >= total) return;
    const int r = t >> 14, rem = t & 16383;
    const int n = rem >> 7, k = rem & 127;
    wt[t] = f2bf(w[(r << 14) + (k << 7) + n]);
}

// ---------------- MFMA GEMM: h[rel_local] = inp @ W[rel_base+rel_local] -----
// 256 thr = 4 waves; tile 128 rows x 128 cols x K=128. Wave w covers cols
// w*32..w*32+31 (N-tiles 2w,2w+1), all 8 M-tiles. A in LDS (row-major,
// LDK-padded); B frags (Wt contiguous-k) in VGPRs for whole kernel.
__global__ __launch_bounds__(256) void mfma_gemm(
    const unsigned short* __restrict__ inpb,
    const unsigned short* __restrict__ wt,
    unsigned short* __restrict__ h, int rel_base, int n_nodes)
{
    __shared__ unsigned short As[128 * LDK];   // 34 KB

    const int rel = rel_base + blockIdx.y;
    const int row0 = blockIdx.x * 128;
    const int tid = threadIdx.x;
    const int wave = tid >> 6, lane = tid & 63;
    const int m = lane & 15, q = lane >> 4;

    // stage A: thread t -> row t/2, half-row (t&1)*64 elems (128 B)
    {
        const int r = tid >> 1;
        const int half = (tid & 1) * 64;
        const int grow = row0 + r;
        const uint4* gp = (const uint4*)(inpb + (size_t)grow * IN + half);
        uint4* lp = (uint4*)&As[r * LDK + half];
        #pragma unroll
        for (int i = 0; i < 8; ++i) {
            uint4 v = make_uint4(0u, 0u, 0u, 0u);
            if (grow < n_nodes) v = gp[i];
            lp[i] = v;
        }
    }

    // B fragments: b[nt][ks][j] = Wt[rel][n0+m][ks*32+q*8+j]
    bf16x8 bfrag[2][4];
    {
        const unsigned short* wtr = wt + ((size_t)rel * OUT + wave * 32) * IN;
        #pragma unroll
        for (int nt = 0; nt < 2; ++nt)
            #pragma unroll
            for (int ks = 0; ks < 4; ++ks)
                bfrag[nt][ks] = *(const bf16x8*)(
                    wtr + (size_t)(nt * 16 + m) * IN + ks * 32 + q * 8);
    }

    __syncthreads();

    f32x4 acc[8][2];
    #pragma unroll
    for (int mt = 0; mt < 8; ++mt)
        #pragma unroll
        for (int nt = 0; nt < 2; ++nt)
            acc[mt][nt] = (f32x4){0.f, 0.f, 0.f, 0.f};

    #pragma unroll
    for (int ks = 0; ks < 4; ++ks) {
        bf16x8 a[8];
        #pragma unroll
        for (int mt = 0; mt < 8; ++mt)
            a[mt] = *(const bf16x8*)&As[(mt * 16 + m) * LDK + ks * 32 + q * 8];
        #pragma unroll
        for (int mt = 0; mt < 8; ++mt) {
            acc[mt][0] = __builtin_amdgcn_mfma_f32_16x16x32_bf16(
                a[mt], bfrag[0][ks], acc[mt][0], 0, 0, 0);
            acc[mt][1] = __builtin_amdgcn_mfma_f32_16x16x32_bf16(
                a[mt], bfrag[1][ks], acc[mt][1], 0, 0, 0);
        }
    }

    // C/D: lane holds rows q*4+0..3, col = nt*16 + m. Store bf16.
    unsigned short* hrel = h + (size_t)blockIdx.y * n_nodes * OUT;
    #pragma unroll
    for (int mt = 0; mt < 8; ++mt) {
        #pragma unroll
        for (int rg = 0; rg < 4; ++rg) {
            const int row = row0 + mt * 16 + q * 4 + rg;
            if (row < n_nodes) {
                unsigned short* hp = hrel + (size_t)row * OUT + wave * 32 + m;
                hp[0]  = f2bf(acc[mt][0][rg]);
                hp[16] = f2bf(acc[mt][1][rg]);
            }
        }
    }
}

// ---------------- bucket fill (no scan) -------------------------------------
__global__ __launch_bounds__(256) void fill_kernel(
    const int* __restrict__ src, const int* __restrict__ dst,
    const float* __restrict__ vals, int* __restrict__ counts,
    int2* __restrict__ bucket, int4* __restrict__ spill,
    int* __restrict__ spill_cnt, int n_edges, int n_nodes,
    int cap, int spill_max)
{
    const int e = blockIdx.x * 256 + threadIdx.x;
    if (e >= n_edges) return;
    const size_t g = (size_t)blockIdx.y * n_edges + e;
    const int d = dst[g];
    const int enc = blockIdx.y * n_nodes + src[g];   // h row index
    const int pos = atomicAdd(&counts[d], 1);
    if (pos < cap) {
        bucket[(size_t)d * cap + pos] = make_int2(enc, __float_as_int(vals[g]));
    } else {
        const int sp = atomicAdd(spill_cnt, 1);
        if (sp < spill_max)
            spill[sp] = make_int4(d, enc, __float_as_int(vals[g]), 0);
    }
}

// ---------------- gather (bf16 h) -------------------------------------------
__global__ __launch_bounds__(256) void gather_kernel(
    const unsigned short* __restrict__ h, const int2* __restrict__ bucket,
    const int* __restrict__ counts, float* __restrict__ out,
    int n_nodes, int cap, int accum)
{
    const int node = blockIdx.x * 8 + (threadIdx.x >> 5);
    const int lane = threadIdx.x & 31;
    if (node >= n_nodes) return;
    int cnt = counts[node];
    if (cnt > cap) cnt = cap;
    const int2* __restrict__ b = bucket + (size_t)node * cap;
    float4* __restrict__ op = (float4*)(out + (size_t)node * OUT);

    float4 acc = accum ? op[lane] : make_float4(0.f, 0.f, 0.f, 0.f);
    int j = 0;
    for (; j + 4 <= cnt; j += 4) {
        const int2 r0 = b[j], r1 = b[j + 1], r2 = b[j + 2], r3 = b[j + 3];
        const uint2 h0 = ((const uint2*)(h + (size_t)r0.x * OUT))[lane];
        const uint2 h1 = ((const uint2*)(h + (size_t)r1.x * OUT))[lane];
        const uint2 h2 = ((const uint2*)(h + (size_t)r2.x * OUT))[lane];
        const uint2 h3 = ((const uint2*)(h + (size_t)r3.x * OUT))[lane];
        const float v0 = __int_as_float(r0.y), v1 = __int_as_float(r1.y);
        const float v2 = __int_as_float(r2.y), v3 = __int_as_float(r3.y);
        acc.x += v0*bflo(h0.x) + v1*bflo(h1.x) + v2*bflo(h2.x) + v3*bflo(h3.x);
        acc.y += v0*bfhi(h0.x) + v1*bfhi(h1.x) + v2*bfhi(h2.x) + v3*bfhi(h3.x);
        acc.z += v0*bflo(h0.y) + v1*bflo(h1.y) + v2*bflo(h2.y) + v3*bflo(h3.y);
        acc.w += v0*bfhi(h0.y) + v1*bfhi(h1.y) + v2*bfhi(h2.y) + v3*bfhi(h3.y);
    }
    for (; j < cnt; ++j) {
        const int2 r0 = b[j];
        const float v = __int_as_float(r0.y);
        const uint2 hv = ((const uint2*)(h + (size_t)r0.x * OUT))[lane];
        acc.x += v * bflo(hv.x); acc.y += v * bfhi(hv.x);
        acc.z += v * bflo(hv.y); acc.w += v * bfhi(hv.y);
    }
    op[lane] = acc;
}

// ---------------- spill cleanup (expected ~0 edges) -------------------------
__global__ __launch_bounds__(256) void spill_kernel(
    const unsigned short* __restrict__ h, const int4* __restrict__ spill,
    const int* __restrict__ spill_cnt, float* __restrict__ out, int spill_max)
{
    int n = *spill_cnt;
    if (n > spill_max) n = spill_max;
    const int w = (blockIdx.x * 256 + threadIdx.x) >> 6;
    const int lane = threadIdx.x & 63;
    const int nw = gridDim.x * 4;
    for (int i = w; i < n; i += nw) {
        const int4 s = spill[i];
        const float v = __int_as_float(s.z);
        const unsigned int u = ((const unsigned int*)(h + (size_t)s.y * OUT))[lane];
        float* __restrict__ orow = out + (size_t)s.x * OUT;
        __hip_atomic_fetch_add(orow + lane * 2,     v * bflo(u),
                               __ATOMIC_RELAXED, __HIP_MEMORY_SCOPE_AGENT);
        __hip_atomic_fetch_add(orow + lane * 2 + 1, v * bfhi(u),
                               __ATOMIC_RELAXED, __HIP_MEMORY_SCOPE_AGENT);
    }
}

// ---------------- last-resort scatter (atomic, bf16 h, per relation) --------
__global__ __launch_bounds__(256) void scatter_kernel(
    const unsigned short* __restrict__ h, const int* __restrict__ src,
    const int* __restrict__ dst, const float* __restrict__ vals,
    float* __restrict__ out, int n_edges)
{
    const int e = blockIdx.x * 8 + (threadIdx.x >> 5);
    if (e >= n_edges) return;
    const int lane = threadIdx.x & 31;
    const int s = src[e];
    const int d = dst[e];
    const float v = vals[e];
    const unsigned int* __restrict__ hrow =
        (const unsigned int*)(h + (size_t)s * OUT);
    float* __restrict__ orow = out + (size_t)d * OUT;
    #pragma unroll
    for (int kk = 0; kk < 2; ++kk) {
        const int jj = lane + kk * 32;      // uint index: cols 2jj, 2jj+1
        const unsigned int u = hrow[jj];
        __hip_atomic_fetch_add(orow + jj * 2,     v * bflo(u),
                               __ATOMIC_RELAXED, __HIP_MEMORY_SCOPE_AGENT);
        __hip_atomic_fetch_add(orow + jj * 2 + 1, v * bfhi(u),
                               __ATOMIC_RELAXED, __HIP_MEMORY_SCOPE_AGENT);
    }
}

extern "C" void kernel_launch(void* const* d_in, const int* in_sizes, int n_in,
                              void* d_out, int out_size, void* d_ws, size_t ws_size,
                              hipStream_t stream) {
    const float* inp     = (const float*)d_in[0];
    const int*   src     = (const int*)  d_in[1];
    const int*   dst     = (const int*)  d_in[2];
    const float* vals    = (const float*)d_in[3];
    const float* weights = (const float*)d_in[4];
    float* out = (float*)d_out;

    const int n_nodes = in_sizes[0] / IN;            // 50000
    const int n_rel   = in_sizes[4] / (IN * OUT);    // 8
    const int n_edges = in_sizes[1] / n_rel;         // 100000

    auto align_up = [](size_t x) { return (x + 255) & ~(size_t)255; };
    const int SPILL_MAX = 65536;
    const size_t sz_inpb   = align_up((size_t)n_nodes * IN * 2);
    const size_t sz_wt     = align_up((size_t)n_rel * IN * OUT * 2);
    const size_t sz_counts = align_up((size_t)(n_nodes + 1) * 4);
    const size_t sz_spill  = align_up((size_t)SPILL_MAX * 16);
    const size_t fixed = sz_inpb + sz_wt + sz_counts + sz_spill;

    const int conv_n8 = n_nodes * IN / 8;
    const int wt_tot  = n_rel * IN * OUT;
    const int gemm_gx = (n_nodes + 127) / 128;
    const int gath_gx = (n_nodes + 7) / 8;
    const int fill_gx = (n_edges + 255) / 256;

    // ---- full path: all relations at once ----
    {
        const size_t sz_h = (size_t)n_rel * n_nodes * OUT * 2;
        int cap = 0;
        const int caps[] = {64, 48, 32, 24, 20};
        for (int c : caps) {
            if (fixed + sz_h + align_up((size_t)n_nodes * c * 8) <= ws_size) {
                cap = c; break;
            }
        }
        if (cap > 0) {
            char* p = (char*)d_ws;
            unsigned short* inpb = (unsigned short*)p;  p += sz_inpb;
            unsigned short* wtb  = (unsigned short*)p;  p += sz_wt;
            int*   counts = (int*)p;    p += sz_counts;
            int4*  spill  = (int4*)p;   p += sz_spill;
            unsigned short* h = (unsigned short*)p;     p += sz_h;
            int2*  bucket = (int2*)p;
            int*   spill_cnt = counts + n_nodes;

            conv_inp_kernel<<<(conv_n8 + 255) / 256, 256, 0, stream>>>(
                inp, inpb, conv_n8);
            conv_w_kernel<<<(wt_tot + 255) / 256, 256, 0, stream>>>(
                weights, wtb, wt_tot);
            hipMemsetAsync(counts, 0, (size_t)(n_nodes + 1) * 4, stream);
            dim3 fg(fill_gx, n_rel);
            fill_kernel<<<fg, 256, 0, stream>>>(src, dst, vals, counts, bucket,
                                                spill, spill_cnt, n_edges,
                                                n_nodes, cap, SPILL_MAX);
            dim3 gg(gemm_gx, n_rel);
            mfma_gemm<<<gg, 256, 0, stream>>>(inpb, wtb, h, 0, n_nodes);
            gather_kernel<<<gath_gx, 256, 0, stream>>>(h, bucket, counts, out,
                                                       n_nodes, cap, 0);
            spill_kernel<<<128, 256, 0, stream>>>(h, spill, spill_cnt, out,
                                                  SPILL_MAX);
            return;
        }
    }

    // ---- per-relation path ----
    {
        const size_t sz_h = (size_t)n_nodes * OUT * 2;
        int cap = 0;
        const int caps[] = {16, 12, 8};
        for (int c : caps) {
            if (fixed + sz_h + align_up((size_t)n_nodes * c * 8) <= ws_size) {
                cap = c; break;
            }
        }
        if (cap > 0) {
            char* p = (char*)d_ws;
            unsigned short* inpb = (unsigned short*)p;  p += sz_inpb;
            unsigned short* wtb  = (unsigned short*)p;  p += sz_wt;
            int*   counts = (int*)p;    p += sz_counts;
            int4*  spill  = (int4*)p;   p += sz_spill;
            unsigned short* h = (unsigned short*)p;     p += sz_h;
            int2*  bucket = (int2*)p;
            int*   spill_cnt = counts + n_nodes;

            conv_inp_kernel<<<(conv_n8 + 255) / 256, 256, 0, stream>>>(
                inp, inpb, conv_n8);
            conv_w_kernel<<<(wt_tot + 255) / 256, 256, 0, stream>>>(
                weights, wtb, wt_tot);
            for (int r = 0; r < n_rel; ++r) {
                const size_t eoff = (size_t)r * n_edges;
                hipMemsetAsync(counts, 0, (size_t)(n_nodes + 1) * 4, stream);
                dim3 fg(fill_gx, 1);
                fill_kernel<<<fg, 256, 0, stream>>>(src + eoff, dst + eoff,
                                                    vals + eoff, counts, bucket,
                                                    spill, spill_cnt, n_edges,
                                                    n_nodes, cap, SPILL_MAX);
                dim3 gg(gemm_gx, 1);
                mfma_gemm<<<gg, 256, 0, stream>>>(inpb, wtb, h, r, n_nodes);
                gather_kernel<<<gath_gx, 256, 0, stream>>>(h, bucket, counts,
                                                           out, n_nodes, cap,
                                                           r > 0 ? 1 : 0);
                spill_kernel<<<128, 256, 0, stream>>>(h, spill, spill_cnt, out,
                                                      SPILL_MAX);
            }
            return;
        }
    }

    // ---- last resort: per-relation gemm + atomic scatter ----
    {
        char* p = (char*)d_ws;
        unsigned short* inpb = (unsigned short*)p;  p += sz_inpb;
        unsigned short* wtb  = (unsigned short*)p;  p += sz_wt;
        unsigned short* h = (unsigned short*)p;

        conv_inp_kernel<<<(conv_n8 + 255) / 256, 256, 0, stream>>>(
            inp, inpb, conv_n8);
        conv_w_kernel<<<(wt_tot + 255) / 256, 256, 0, stream>>>(
            weights, wtb, wt_tot);
        hipMemsetAsync(out, 0, (size_t)n_nodes * OUT * 4, stream);
        const int sgx = (n_edges + 7) / 8;
        for (int r = 0; r < n_rel; ++r) {
            const size_t eoff = (size_t)r * n_edges;
            dim3 gg(gemm_gx, 1);
            mfma_gemm<<<gg, 256, 0, stream>>>(inpb, wtb, h, r, n_nodes);
            scatter_kernel<<<sgx, 256, 0, stream>>>(h, src + eoff, dst + eoff,
                                                    vals + eoff, out, n_edges);
        }
    }
}